// Round 1
// baseline (194.555 us; speedup 1.0000x reference)
//
#include <hip/hip_runtime.h>

// QFD loss: out = 0.1 * sum_b diff_b^T A diff_b, A_ij = 1 - |i-j|/85.
// Identity: q = S^2 - (2/85) * (S*sumL - sumL2), where
//   L_k = prefix sums of d, sumL = sum_{k<84} L_k, sumL2 = sum_{k<84} L_k^2.
//
// R6: R5 (single-shot blocks, stage->vmcnt(0) drain->compute->die) was
// structure-bound at 2.7 TB/s: L3-resident dispatches ran the SAME 66 us as
// HBM-fed ones -> not source-BW-bound; the vmcnt(0) full drain per block +
// zero stage/compute overlap + 4096 short blocks idled the memory system
// ~55% of the time. Fix: persistent blocks (3/CU), double-buffered 32-row
// chunks (same 45 KB LDS -> same residency), prefetch chunk t+1 via
// global_load_lds BEFORE computing chunk t, one __syncthreads per chunk
// (T3 minimum-2-phase template; race-free with plain barriers).

#define QFD_D 85
#define ROWS_PER_CHUNK 32
#define THREADS 128
#define NWAVES (THREADS / 64)
#define F4_PER_CHUNK 680          // 32*85/4 float4s per array per chunk
#define ROUNDS 11                 // ceil(680/64); tail 680..703 = clamped junk
#define BUF_FLOATS (ROUNDS * 256) // 2816 floats = 11264 B per array per buffer

typedef __attribute__((address_space(1))) const void glob_cv;
typedef __attribute__((address_space(3))) void lds_v;

__global__ __launch_bounds__(THREADS) void qfd_kernel(
    const float* __restrict__ in, const float* __restrict__ tgt,
    float* __restrict__ partial, int nchunks) {
    // 2 buffers x 2 arrays x 11264 B = 45056 B -> 3 blocks/CU (135 KB < 160 KB)
    __shared__ float lin[2][BUF_FLOATS];
    __shared__ float ltg[2][BUF_FLOATS];
    __shared__ float wsum[NWAVES];

    const int tid  = threadIdx.x;
    const int lane = tid & 63;
    const int wave = tid >> 6;

    const float4* in4 = reinterpret_cast<const float4*>(in);
    const float4* tg4 = reinterpret_cast<const float4*>(tgt);

    // Segmented per-row scan geometry (verified in R5): thread = 4*row + q.
    // Segments: q0=[0,22) len 22, q1=[22,43), q2=[43,64), q3=[64,85) len 21.
    const int q   = tid & 3;
    const int row = tid >> 2;                  // 0..31
    const int off = 21 * q + (q != 0);         // 0,22,43,64
    const int p   = row * QFD_D + off;
    const int qb  = lane & 60;
    const float len = (q == 0) ? 22.0f : 21.0f;

    float acc = 0.0f;

    // ---- Prologue: stage first chunk into buffer 0 ----
    {
        const float4* ia = in4 + (long)blockIdx.x * F4_PER_CHUNK;
        const float4* ta = tg4 + (long)blockIdx.x * F4_PER_CHUNK;
        for (int r = wave; r < ROUNDS; r += NWAVES) {
            int idx = r * 64 + lane;
            int g = idx < F4_PER_CHUNK ? idx : 0;   // clamp tail (junk, never read)
            __builtin_amdgcn_global_load_lds(
                (glob_cv*)(ia + g), (lds_v*)&lin[0][r * 256], 16, 0, 0);
            __builtin_amdgcn_global_load_lds(
                (glob_cv*)(ta + g), (lds_v*)&ltg[0][r * 256], 16, 0, 0);
        }
    }
    __syncthreads();   // vmcnt(0) drain: chunk 0 resident

    int cur = 0;
    for (int c = blockIdx.x; c < nchunks; c += gridDim.x) {
        // ---- Prefetch chunk t+1 into the other buffer (in flight during
        // the compute below; drained by the __syncthreads at loop bottom) ----
        const int cn = c + (int)gridDim.x;
        if (cn < nchunks) {
            const float4* ia = in4 + (long)cn * F4_PER_CHUNK;
            const float4* ta = tg4 + (long)cn * F4_PER_CHUNK;
            for (int r = wave; r < ROUNDS; r += NWAVES) {
                int idx = r * 64 + lane;
                int g = idx < F4_PER_CHUNK ? idx : 0;
                __builtin_amdgcn_global_load_lds(
                    (glob_cv*)(ia + g), (lds_v*)&lin[cur ^ 1][r * 256], 16, 0, 0);
                __builtin_amdgcn_global_load_lds(
                    (glob_cv*)(ta + g), (lds_v*)&ltg[cur ^ 1][r * 256], 16, 0, 0);
            }
        }

        // ---- Compute current chunk from buf[cur] ----
        const float* Li = &lin[cur][0];
        const float* Lt = &ltg[cur][0];
        float l = 0.0f, a1 = 0.0f, b2 = 0.0f;
        #pragma unroll
        for (int j = 0; j < 21; ++j) {
            float v = fabsf(Li[p + j] - Lt[p + j]);
            l += v;
            a1 += l;
            b2 = fmaf(l, l, b2);
        }
        if (q == 0) {                          // segment 0 has 22 elements
            float v = fabsf(Li[p + 21] - Lt[p + 21]);
            l += v;
            a1 += l;
            b2 = fmaf(l, l, b2);
        }

        // Quad combine via shuffles. P = exclusive prefix of seg sums.
        float s0 = __shfl(l, qb + 0, 64);
        float s1 = __shfl(l, qb + 1, 64);
        float s2 = __shfl(l, qb + 2, 64);
        float s3 = __shfl(l, qb + 3, 64);
        float S  = (s0 + s1) + (s2 + s3);
        float P  = (q > 0 ? s0 : 0.0f) + (q > 1 ? s1 : 0.0f) + (q > 2 ? s2 : 0.0f);
        float c1 = fmaf(len, P, a1);
        float c2 = fmaf(len * P, P, fmaf(2.0f * P, a1, b2));
        float c1s = __shfl(c1, qb + 0, 64) + __shfl(c1, qb + 1, 64)
                  + __shfl(c1, qb + 2, 64) + __shfl(c1, qb + 3, 64);
        float c2s = __shfl(c2, qb + 0, 64) + __shfl(c2, qb + 1, 64)
                  + __shfl(c2, qb + 2, 64) + __shfl(c2, qb + 3, 64);
        float sumL  = c1s - S;
        float sumL2 = c2s - S * S;
        float qrow  = fmaf(S, S, -(2.0f / 85.0f) * (S * sumL - sumL2));
        if (q == 0) acc += qrow;

        __syncthreads();   // drains prefetch DMA + guards buf reuse
        cur ^= 1;
    }

    // ---- Final block reduction -> one plain store per block ----
    float val = acc;
    #pragma unroll
    for (int m = 32; m > 0; m >>= 1)
        val += __shfl_xor(val, m, 64);
    if (lane == 0) wsum[wave] = val;
    __syncthreads();
    if (tid == 0) {
        float s = 0.0f;
        #pragma unroll
        for (int w = 0; w < NWAVES; ++w) s += wsum[w];
        partial[blockIdx.x] = s;
    }
}

// Stage 2: reduce n partials (n = grid), write 0.1 * sum. One block.
__global__ __launch_bounds__(THREADS) void qfd_reduce_kernel(
    const float* __restrict__ partial, float* __restrict__ out, int n) {
    __shared__ float wsum[NWAVES];
    const int tid = threadIdx.x;
    float s = 0.0f;
    for (int i = tid; i < n; i += THREADS) s += partial[i];
    #pragma unroll
    for (int m = 32; m > 0; m >>= 1)
        s += __shfl_xor(s, m, 64);
    if ((tid & 63) == 0) wsum[tid >> 6] = s;
    __syncthreads();
    if (tid == 0) {
        float t = 0.0f;
        #pragma unroll
        for (int w = 0; w < NWAVES; ++w) t += wsum[w];
        out[0] = 0.1f * t;
    }
}

extern "C" void kernel_launch(void* const* d_in, const int* in_sizes, int n_in,
                              void* d_out, int out_size, void* d_ws, size_t ws_size,
                              hipStream_t stream) {
    const float* in  = (const float*)d_in[0];
    const float* tgt = (const float*)d_in[1];
    float* out = (float*)d_out;
    float* partial = (float*)d_ws;             // up to 4096 floats = 16 KB scratch

    const int B = in_sizes[0] / QFD_D;         // 262144
    const int nchunks = B / ROWS_PER_CHUNK;    // 8192
    int grid = 256 * 3;                        // persistent: 3 blocks/CU (LDS-bound)
    if (grid > nchunks) grid = nchunks;

    qfd_kernel<<<grid, THREADS, 0, stream>>>(in, tgt, partial, nchunks);
    qfd_reduce_kernel<<<1, THREADS, 0, stream>>>(partial, out, grid);
}